// Round 5
// baseline (425.975 us; speedup 1.0000x reference)
//
#include <hip/hip_runtime.h>

// B=4, N=10, C=256, Lq=Ls=1024, K=5, G=2.  TQ=64, TS=32.  fp16 MFMA path.
#define CQ_ELEMS (4 * 256 * 1024)
#define CS_ELEMS (10 * 256 * 1024)
#define OUT2_OFF 2097152

typedef __attribute__((ext_vector_type(8))) _Float16 f16x8;
typedef __attribute__((ext_vector_type(4))) float f32x4;

// ws layout (bytes): [0..255] float means[2];
//   Sh[n][s][c] fp16, Sv[n][c][s] fp16, Qt[b][q][c] fp16
#define WS_SH 256
#define SH_ELEMS (10 * 1024 * 256)
#define SV_ELEMS (10 * 256 * 1024)

// ---------------------------------------------------------------------------
__global__ __launch_bounds__(256) void means_kernel(const float* __restrict__ q,
                                                    const float* __restrict__ s,
                                                    float* __restrict__ ws) {
    const int tid = blockIdx.x * 256 + threadIdx.x;
    const int stride = gridDim.x * 256;
    float sq = 0.f, ss = 0.f;
    const float4* q4 = (const float4*)q;
    const float4* s4 = (const float4*)s;
    for (int i = tid; i < CQ_ELEMS / 4; i += stride) {
        float4 v = q4[i];
        sq += (v.x + v.y) + (v.z + v.w);
    }
    for (int i = tid; i < CS_ELEMS / 4; i += stride) {
        float4 v = s4[i];
        ss += (v.x + v.y) + (v.z + v.w);
    }
#pragma unroll
    for (int off = 32; off > 0; off >>= 1) {
        sq += __shfl_down(sq, off, 64);
        ss += __shfl_down(ss, off, 64);
    }
    __shared__ float redq[4], reds[4];
    const int lane = threadIdx.x & 63, wid = threadIdx.x >> 6;
    if (lane == 0) { redq[wid] = sq; reds[wid] = ss; }
    __syncthreads();
    if (threadIdx.x == 0) {
        atomicAdd(&ws[0], (redq[0] + redq[1]) + (redq[2] + redq[3]));
        atomicAdd(&ws[1], (reds[0] + reds[1]) + (reds[2] + reds[3]));
    }
}

// ---------------------------------------------------------------------------
// Centered fp16 conversion.  z<10: S -> Sv [c][s] + Sh [s][c] + zero out2.
// z>=10: Q -> q_out (fp32, both g-copies) + Qt [q][c].
// ---------------------------------------------------------------------------
__global__ __launch_bounds__(256) void convert_kernel(const float* __restrict__ Q,
                                                      const float* __restrict__ S,
                                                      const float* __restrict__ ws,
                                                      unsigned short* __restrict__ sh,
                                                      unsigned short* __restrict__ sv,
                                                      unsigned short* __restrict__ qt,
                                                      float* __restrict__ out) {
    __shared__ unsigned short Th[32][40];
    const int t = threadIdx.x;
    const int x0 = blockIdx.x << 5;   // s (or q) tile base
    const int c0 = blockIdx.y << 5;   // c tile base
    const int z = blockIdx.z;

    const int cl = t >> 3, x4 = (t & 7) << 2;

    if (z < 10) {
        const int n = z;
        const float ms = ws[1] * (1.0f / (float)CS_ELEMS);
        float4 v = *(const float4*)(S + ((size_t)(n * 256 + c0 + cl)) * 1024 + x0 + x4);
        float x[4] = {v.x - ms, v.y - ms, v.z - ms, v.w - ms};
        unsigned short hb[4];
#pragma unroll
        for (int j = 0; j < 4; ++j) {
            _Float16 h = (_Float16)x[j];
            hb[j] = __builtin_bit_cast(unsigned short, h);
            Th[cl][x4 + j] = hb[j];
        }
        *(ushort4*)(sv + ((size_t)(n * 256 + c0 + cl)) * 1024 + x0 + x4) =
            make_ushort4(hb[0], hb[1], hb[2], hb[3]);
        // zero the atomically-accumulated 'aligned' half of d_out (8 MB over 2560 blocks)
        {
            const int lin = (z * 8 + blockIdx.y) * 32 + blockIdx.x;
            const int gid = lin * 256 + t;
            if (gid < 524288) ((int4*)(out + OUT2_OFF))[gid] = make_int4(0, 0, 0, 0);
        }
        __syncthreads();
        const int sl = t >> 3, c4 = (t & 7) << 2;
        *(ushort4*)(sh + ((size_t)(n * 1024 + x0 + sl)) * 256 + c0 + c4) =
            make_ushort4(Th[c4 + 0][sl], Th[c4 + 1][sl], Th[c4 + 2][sl], Th[c4 + 3][sl]);
    } else {
        const int b = z - 10;
        const float mq = ws[0] * (1.0f / (float)CQ_ELEMS);
        float4 v = *(const float4*)(Q + ((size_t)(b * 256 + c0 + cl)) * 1024 + x0 + x4);
        v.x -= mq; v.y -= mq; v.z -= mq; v.w -= mq;
        float* o = out + ((size_t)(b * 2) * 256 + (c0 + cl)) * 1024 + x0 + x4;
        *(float4*)o = v;
        *(float4*)(o + 256 * 1024) = v;
        float x[4] = {v.x, v.y, v.z, v.w};
#pragma unroll
        for (int j = 0; j < 4; ++j) {
            _Float16 h = (_Float16)x[j];
            Th[cl][x4 + j] = __builtin_bit_cast(unsigned short, h);
        }
        __syncthreads();
        const int ql = t >> 3, c4 = (t & 7) << 2;
        *(ushort4*)(qt + ((size_t)(b * 1024 + x0 + ql)) * 256 + c0 + c4) =
            make_ushort4(Th[c4 + 0][ql], Th[c4 + 1][ql], Th[c4 + 2][ql], Th[c4 + 3][ql]);
    }
}

// ---------------------------------------------------------------------------
// Fused flash attention, fp16 MFMA.  Block = (64-q tile, bn pair), 4 waves.
// s1 is FRAG-MAJOR: off16 = (f*2+nt)*64 + quad*16 + (sl ^ rot(u&7)), where
// u = c>>3, sl = s>>1, nt = s&1 (even/odd s pairing for packed-b32 P writes),
// rot(u) = ((u<<1)|(u>>2))&7.  Staging writes and frag reads both hit 8
// distinct bank-groups per 8-lane phase -> conflict-free.  Next-step global
// tiles are prefetched into registers during compute.
// NOTE: __launch_bounds__(256,2) — (256,3) caps unified VGPR+AGPR at ~170,
// which spilled the prefetch regs to scratch (R4: WRITE_SIZE 686 MB ~= the
// exact scratch volume).  Occupancy is grid-limited at ~2.5 blocks/CU anyway.
// ---------------------------------------------------------------------------
union __align__(16) SMem {
    struct {
        unsigned short s1[8192];     // frag-major QK B-tile, 16 KB
        unsigned short s2[256][40];  // V^T fp16 [c][s], 80 B rows (conflict-free: 5x16B)
        unsigned short pb[64][40];   // P fp16 [q][s], 80 B rows
    } st;
    float epi[2][64][68];            // epilogue staging (aliases)
};

__device__ __forceinline__ int rot3(int u) { return ((u << 1) | (u >> 2)) & 7; }

__global__ __launch_bounds__(256, 2) void attn_kernel(const unsigned short* __restrict__ qt,
                                                      const unsigned short* __restrict__ sh,
                                                      const unsigned short* __restrict__ sv,
                                                      float* __restrict__ out) {
    __shared__ SMem sm;
    __shared__ float alpha_s[64];
    __shared__ float lfin[64];

    const int t = threadIdx.x;
    const int w = t >> 6;
    const int lane = t & 63;
    const int quad = lane >> 4;
    const int l16 = lane & 15;

    const int q0 = blockIdx.x << 6;   // 16 q-tiles
    const int bn = blockIdx.y;        // 40
    const int b = bn / 10;
    const int n = bn - b * 10;
    const int g = n / 5;

    const unsigned short* __restrict__ Shn = sh + (size_t)n * (1024 * 256);
    const unsigned short* __restrict__ Svn = sv + (size_t)n * (256 * 1024);

    // ---- Q A-frags: wave w owns q rows q0+16w .. +15 ----
    f16x8 qf[8];
    {
        const unsigned short* qp = qt + (size_t)(b * 1024 + q0 + 16 * w + l16) * 256 + quad * 8;
#pragma unroll
        for (int f = 0; f < 8; ++f)
            qf[f] = *(const f16x8*)(qp + f * 32);
    }

    f32x4 O[4][4];   // O^T: c = 64w+16mt+4quad+r, q = 16nt+l16
#pragma unroll
    for (int mt = 0; mt < 4; ++mt)
#pragma unroll
        for (int nt = 0; nt < 4; ++nt) O[mt][nt] = (f32x4){0.f, 0.f, 0.f, 0.f};

    float m_run[4], l_run[4];
#pragma unroll
    for (int r = 0; r < 4; ++r) { m_run[r] = -1e30f; l_run[r] = 0.f; }

    // staging maps
    const int srow = t >> 3;               // s row 0..31 (this thread stages)
    const int sl = srow >> 1, ntw = srow & 1;
    const int c4 = t >> 2, ck = t & 3;     // s2 map

    int4 p1[4], p2[4];
    {
        const unsigned short* g1 = Shn + (size_t)srow * 256;
#pragma unroll
        for (int it = 0; it < 4; ++it)
            p1[it] = *(const int4*)(g1 + ((t & 7) + 8 * it) * 8);
#pragma unroll
        for (int it = 0; it < 4; ++it)
            p2[it] = *(const int4*)(Svn + (size_t)(c4 + 64 * it) * 1024 + ck * 8);
    }

    for (int s0i = 0; s0i < 32; ++s0i) {
        __syncthreads();   // prior-step LDS reads complete

        // ---- write prefetched tiles to LDS ----
#pragma unroll
        for (int it = 0; it < 4; ++it) {
            const int u = (t & 7) + 8 * it;
            const int slot = sl ^ rot3(u & 7);
            const int off16 = ((u >> 2) * 2 + ntw) * 64 + (u & 3) * 16 + slot;
            *(int4*)&sm.st.s1[off16 * 8] = p1[it];
        }
#pragma unroll
        for (int it = 0; it < 4; ++it)
            *(int4*)&sm.st.s2[c4 + 64 * it][ck * 8] = p2[it];
        __syncthreads();

        // ---- prefetch next step (awaited at next iteration's LDS write) ----
        if (s0i < 31) {
            const int s0n = (s0i + 1) << 5;
            const unsigned short* g1 = Shn + (size_t)(s0n + srow) * 256;
#pragma unroll
            for (int it = 0; it < 4; ++it)
                p1[it] = *(const int4*)(g1 + ((t & 7) + 8 * it) * 8);
#pragma unroll
            for (int it = 0; it < 4; ++it)
                p2[it] = *(const int4*)(Svn + (size_t)(c4 + 64 * it) * 1024 + s0n + ck * 8);
        }

        // ---- QK^T: sim[16q x 32s] ----
        f32x4 sim0 = (f32x4){0.f, 0.f, 0.f, 0.f};
        f32x4 sim1 = (f32x4){0.f, 0.f, 0.f, 0.f};
#pragma unroll
        for (int f = 0; f < 8; ++f) {
            const int slot = l16 ^ rot3((4 * f + quad) & 7);
            const unsigned short* base = &sm.st.s1[((f * 2) * 64 + quad * 16 + slot) * 8];
            f16x8 b0 = *(const f16x8*)base;           // nt=0: true s = 2*l16
            f16x8 b1 = *(const f16x8*)(base + 512);   // nt=1: true s = 2*l16+1
            sim0 = __builtin_amdgcn_mfma_f32_16x16x32_f16(qf[f], b0, sim0, 0, 0, 0);
            sim1 = __builtin_amdgcn_mfma_f32_16x16x32_f16(qf[f], b1, sim1, 0, 0, 0);
        }

        // ---- online softmax (rows q = 16w+4quad+r; reduce over l16) ----
        float rowmax[4];
#pragma unroll
        for (int r = 0; r < 4; ++r) rowmax[r] = fmaxf(sim0[r], sim1[r]);
#pragma unroll
        for (int off = 1; off <= 8; off <<= 1)
#pragma unroll
            for (int r = 0; r < 4; ++r)
                rowmax[r] = fmaxf(rowmax[r], __shfl_xor(rowmax[r], off, 64));

        float al[4], rs[4], pv0[4], pv1[4];
#pragma unroll
        for (int r = 0; r < 4; ++r) {
            const float mn = fmaxf(m_run[r], rowmax[r]);
            al[r] = __expf(m_run[r] - mn);
            m_run[r] = mn;
            pv0[r] = __expf(sim0[r] - mn);
            pv1[r] = __expf(sim1[r] - mn);
            rs[r] = pv0[r] + pv1[r];
        }
#pragma unroll
        for (int off = 1; off <= 8; off <<= 1)
#pragma unroll
            for (int r = 0; r < 4; ++r) rs[r] += __shfl_xor(rs[r], off, 64);
#pragma unroll
        for (int r = 0; r < 4; ++r) l_run[r] = l_run[r] * al[r] + rs[r];

        // ---- publish P (fp16 pairs, b32) and alpha ----
#pragma unroll
        for (int r = 0; r < 4; ++r) {
            union { _Float16 h[2]; unsigned u; } pk;
            pk.h[0] = (_Float16)pv0[r];
            pk.h[1] = (_Float16)pv1[r];
            *(unsigned*)&sm.st.pb[16 * w + 4 * quad + r][l16 * 2] = pk.u;
        }
        if (l16 == 0) {
#pragma unroll
            for (int r = 0; r < 4; ++r) alpha_s[16 * w + 4 * quad + r] = al[r];
        }
        __syncthreads();

        // ---- rescale O^T, then O^T += V^T * P^T ----
#pragma unroll
        for (int nt = 0; nt < 4; ++nt) {
            const float a = alpha_s[16 * nt + l16];
#pragma unroll
            for (int mt = 0; mt < 4; ++mt) {
                O[mt][nt][0] *= a; O[mt][nt][1] *= a; O[mt][nt][2] *= a; O[mt][nt][3] *= a;
            }
        }
        f16x8 vf[4], pf[4];
#pragma unroll
        for (int mt = 0; mt < 4; ++mt)
            vf[mt] = *(const f16x8*)&sm.st.s2[64 * w + 16 * mt + l16][quad * 8];
#pragma unroll
        for (int nt = 0; nt < 4; ++nt)
            pf[nt] = *(const f16x8*)&sm.st.pb[16 * nt + l16][quad * 8];
#pragma unroll
        for (int mt = 0; mt < 4; ++mt)
#pragma unroll
            for (int nt = 0; nt < 4; ++nt)
                O[mt][nt] = __builtin_amdgcn_mfma_f32_16x16x32_f16(vf[mt], pf[nt], O[mt][nt], 0, 0, 0);
    }

    // ---- epilogue ----
    if (l16 == 0) {
#pragma unroll
        for (int r = 0; r < 4; ++r) lfin[16 * w + 4 * quad + r] = l_run[r];
    }
    __syncthreads();

    float linv[4];
#pragma unroll
    for (int nt = 0; nt < 4; ++nt) linv[nt] = 0.2f / lfin[16 * nt + l16];

    float* __restrict__ out2 = out + OUT2_OFF + (size_t)((g << 2) + b) * (256 * 1024);

#pragma unroll
    for (int h = 0; h < 2; ++h) {
        if ((w >> 1) == h) {
            const int we = w & 1;
#pragma unroll
            for (int mt = 0; mt < 4; ++mt)
#pragma unroll
                for (int nt = 0; nt < 4; ++nt)
#pragma unroll
                    for (int r = 0; r < 4; ++r)
                        sm.epi[we][16 * mt + 4 * quad + r][16 * nt + l16] = O[mt][nt][r] * linv[nt];
        }
        __syncthreads();
#pragma unroll 4
        for (int i = 0; i < 32; ++i) {
            const int ro = w * 32 + i;   // 0..127 -> c = 128h + ro
            const float v = sm.epi[ro >> 6][ro & 63][lane];
            atomicAdd(out2 + (size_t)(h * 128 + ro) * 1024 + q0 + lane, v);
        }
        __syncthreads();
    }
}

// ---------------------------------------------------------------------------
extern "C" void kernel_launch(void* const* d_in, const int* in_sizes, int n_in,
                              void* d_out, int out_size, void* d_ws, size_t ws_size,
                              hipStream_t stream) {
    const float* q = (const float*)d_in[0];
    const float* s = (const float*)d_in[1];
    float* out = (float*)d_out;
    float* ws = (float*)d_ws;
    unsigned short* sh = (unsigned short*)((char*)d_ws + WS_SH);
    unsigned short* sv = sh + SH_ELEMS;
    unsigned short* qt = sv + SV_ELEMS;

    hipMemsetAsync(d_ws, 0, 2 * sizeof(float), stream);

    means_kernel<<<256, 256, 0, stream>>>(q, s, ws);
    convert_kernel<<<dim3(32, 8, 14), 256, 0, stream>>>(q, s, ws, sh, sv, qt, out);
    attn_kernel<<<dim3(16, 40), 256, 0, stream>>>(qt, sh, sv, out);
}

// Round 6
// 198.241 us; speedup vs baseline: 2.1488x; 2.1488x over previous
//
#include <hip/hip_runtime.h>

// B=4, N=10, C=256, Lq=Ls=1024, K=5, G=2.  TQ=64, TS=32.  fp16 MFMA path.
#define CQ_ELEMS (4 * 256 * 1024)
#define CS_ELEMS (10 * 256 * 1024)
#define OUT2_OFF 2097152

typedef __attribute__((ext_vector_type(8))) _Float16 f16x8;
typedef __attribute__((ext_vector_type(4))) float f32x4;

// ws layout (bytes): [0..255] float means[2];
//   Sh[n][s][c] fp16, Sv[n][c][s] fp16, Qt[b][q][c] fp16
#define WS_SH 256
#define SH_ELEMS (10 * 1024 * 256)
#define SV_ELEMS (10 * 256 * 1024)

// direct global->LDS DMA, 16 B per lane; LDS dest = wave-uniform base + lane*16
__device__ __forceinline__ void gload_lds16(const unsigned short* g, unsigned short* l) {
    __builtin_amdgcn_global_load_lds(
        (const __attribute__((address_space(1))) void*)g,
        (__attribute__((address_space(3))) void*)l, 16, 0, 0);
}

// ---------------------------------------------------------------------------
__global__ __launch_bounds__(256) void means_kernel(const float* __restrict__ q,
                                                    const float* __restrict__ s,
                                                    float* __restrict__ ws) {
    const int tid = blockIdx.x * 256 + threadIdx.x;
    const int stride = gridDim.x * 256;
    float sq = 0.f, ss = 0.f;
    const float4* q4 = (const float4*)q;
    const float4* s4 = (const float4*)s;
    for (int i = tid; i < CQ_ELEMS / 4; i += stride) {
        float4 v = q4[i];
        sq += (v.x + v.y) + (v.z + v.w);
    }
    for (int i = tid; i < CS_ELEMS / 4; i += stride) {
        float4 v = s4[i];
        ss += (v.x + v.y) + (v.z + v.w);
    }
#pragma unroll
    for (int off = 32; off > 0; off >>= 1) {
        sq += __shfl_down(sq, off, 64);
        ss += __shfl_down(ss, off, 64);
    }
    __shared__ float redq[4], reds[4];
    const int lane = threadIdx.x & 63, wid = threadIdx.x >> 6;
    if (lane == 0) { redq[wid] = sq; reds[wid] = ss; }
    __syncthreads();
    if (threadIdx.x == 0) {
        atomicAdd(&ws[0], (redq[0] + redq[1]) + (redq[2] + redq[3]));
        atomicAdd(&ws[1], (reds[0] + reds[1]) + (reds[2] + reds[3]));
    }
}

// ---------------------------------------------------------------------------
// Centered fp16 conversion.  z<10: S -> Sv [c][s] + Sh [s][c] + zero out2.
// z>=10: Q -> q_out (fp32, both g-copies) + Qt [q][c].
// ---------------------------------------------------------------------------
__global__ __launch_bounds__(256) void convert_kernel(const float* __restrict__ Q,
                                                      const float* __restrict__ S,
                                                      const float* __restrict__ ws,
                                                      unsigned short* __restrict__ sh,
                                                      unsigned short* __restrict__ sv,
                                                      unsigned short* __restrict__ qt,
                                                      float* __restrict__ out) {
    __shared__ unsigned short Th[32][40];
    const int t = threadIdx.x;
    const int x0 = blockIdx.x << 5;   // s (or q) tile base
    const int c0 = blockIdx.y << 5;   // c tile base
    const int z = blockIdx.z;

    const int cl = t >> 3, x4 = (t & 7) << 2;

    if (z < 10) {
        const int n = z;
        const float ms = ws[1] * (1.0f / (float)CS_ELEMS);
        float4 v = *(const float4*)(S + ((size_t)(n * 256 + c0 + cl)) * 1024 + x0 + x4);
        float x[4] = {v.x - ms, v.y - ms, v.z - ms, v.w - ms};
        unsigned short hb[4];
#pragma unroll
        for (int j = 0; j < 4; ++j) {
            _Float16 h = (_Float16)x[j];
            hb[j] = __builtin_bit_cast(unsigned short, h);
            Th[cl][x4 + j] = hb[j];
        }
        *(ushort4*)(sv + ((size_t)(n * 256 + c0 + cl)) * 1024 + x0 + x4) =
            make_ushort4(hb[0], hb[1], hb[2], hb[3]);
        // zero the atomically-accumulated 'aligned' half of d_out (8 MB over 2560 blocks)
        {
            const int lin = (z * 8 + blockIdx.y) * 32 + blockIdx.x;
            const int gid = lin * 256 + t;
            if (gid < 524288) ((int4*)(out + OUT2_OFF))[gid] = make_int4(0, 0, 0, 0);
        }
        __syncthreads();
        const int sl = t >> 3, c4 = (t & 7) << 2;
        *(ushort4*)(sh + ((size_t)(n * 1024 + x0 + sl)) * 256 + c0 + c4) =
            make_ushort4(Th[c4 + 0][sl], Th[c4 + 1][sl], Th[c4 + 2][sl], Th[c4 + 3][sl]);
    } else {
        const int b = z - 10;
        const float mq = ws[0] * (1.0f / (float)CQ_ELEMS);
        float4 v = *(const float4*)(Q + ((size_t)(b * 256 + c0 + cl)) * 1024 + x0 + x4);
        v.x -= mq; v.y -= mq; v.z -= mq; v.w -= mq;
        float* o = out + ((size_t)(b * 2) * 256 + (c0 + cl)) * 1024 + x0 + x4;
        *(float4*)o = v;
        *(float4*)(o + 256 * 1024) = v;
        float x[4] = {v.x, v.y, v.z, v.w};
#pragma unroll
        for (int j = 0; j < 4; ++j) {
            _Float16 h = (_Float16)x[j];
            Th[cl][x4 + j] = __builtin_bit_cast(unsigned short, h);
        }
        __syncthreads();
        const int ql = t >> 3, c4 = (t & 7) << 2;
        *(ushort4*)(qt + ((size_t)(b * 1024 + x0 + ql)) * 256 + c0 + c4) =
            make_ushort4(Th[c4 + 0][ql], Th[c4 + 1][ql], Th[c4 + 2][ql], Th[c4 + 3][ql]);
    }
}

// ---------------------------------------------------------------------------
// Fused flash attention, fp16 MFMA, DMA staging (global_load_lds width=16).
// Block = (64-q tile, bn pair), 4 waves.
// s1 (16 KB): frag-major.  slot16 p = (f*2+nt)*64 + quad*16 + l16 holds
//   Sh[s0 + 2*l16 + nt][f*32 + quad*8 .. +7].  Frag reads are consecutive-lane
//   16 B -> conflict-free.  Wave w DMAs groups fidx=4w..4w+3 (gather on the
//   global side; Sh is L2-resident).
// s2 (16 KB): slot16 p holds V^T[c = p>>2][chunk = (p&3) ^ ((c>>2)&3)];
//   read p = c*4 + (quad ^ ((l16>>2)&3)) -> 2-way (free, m136).
// pb: P [q][s] 80 B rows; alpha at cols 32-33, lfin at cols 34-35 (padding).
// NO register prefetch (R4/R5: compiler spills cross-barrier prefetch arrays
// to scratch regardless of launch_bounds -> 400+ MB WRITE_SIZE).
// ---------------------------------------------------------------------------
union __align__(16) SMem {
    struct {
        unsigned short s1[8192];     // 16 KB
        unsigned short s2[8192];     // 16 KB
        unsigned short pb[64][40];   // 5 KB (cols 32+: alpha/lfin floats)
    } st;
    float epi[2][64][68];            // 34816 B, aliases s1+s2+pb[0..25] at epilogue
};

__global__ __launch_bounds__(256, 3) void attn_kernel(const unsigned short* __restrict__ qt,
                                                      const unsigned short* __restrict__ sh,
                                                      const unsigned short* __restrict__ sv,
                                                      float* __restrict__ out) {
    __shared__ SMem sm;

    const int t = threadIdx.x;
    const int w = t >> 6;
    const int lane = t & 63;
    const int quad = lane >> 4;
    const int l16 = lane & 15;

    const int q0 = blockIdx.x << 6;   // 16 q-tiles
    const int bn = blockIdx.y;        // 40
    const int b = bn / 10;
    const int n = bn - b * 10;
    const int g = n / 5;

    const unsigned short* __restrict__ Shn = sh + (size_t)n * (1024 * 256);
    const unsigned short* __restrict__ Svn = sv + (size_t)n * (256 * 1024);

    // ---- Q A-frags: wave w owns q rows q0+16w .. +15 ----
    f16x8 qf[8];
    {
        const unsigned short* qp = qt + (size_t)(b * 1024 + q0 + 16 * w + l16) * 256 + quad * 8;
#pragma unroll
        for (int f = 0; f < 8; ++f)
            qf[f] = *(const f16x8*)(qp + f * 32);
    }

    f32x4 O[4][4];   // O^T: c = 64w+16mt+4quad+r, q = 16nt+l16
#pragma unroll
    for (int mt = 0; mt < 4; ++mt)
#pragma unroll
        for (int nt = 0; nt < 4; ++nt) O[mt][nt] = (f32x4){0.f, 0.f, 0.f, 0.f};

    float m_run[4], l_run[4];
#pragma unroll
    for (int r = 0; r < 4; ++r) { m_run[r] = -1e30f; l_run[r] = 0.f; }

    for (int s0i = 0; s0i < 32; ++s0i) {
        const int s0 = s0i << 5;
        __syncthreads();   // all waves done reading previous tiles

        // ---- DMA-stage s1 and s2 (wave w: 4 groups of 64 slots each) ----
#pragma unroll
        for (int j = 0; j < 4; ++j) {
            const int fidx = 4 * w + j;
            const unsigned short* g1 = Shn +
                (size_t)(s0 + 2 * (lane & 15) + (fidx & 1)) * 256 + (fidx >> 1) * 32 + (lane >> 4) * 8;
            gload_lds16(g1, &sm.st.s1[fidx * 512]);
            const unsigned short* g2 = Svn +
                (size_t)(w * 64 + j * 16 + (lane >> 2)) * 1024 + s0 + ((lane & 3) ^ (lane >> 4)) * 8;
            gload_lds16(g2, &sm.st.s2[fidx * 512]);
        }
        __syncthreads();   // compiler drains vmcnt before barrier -> tiles ready

        // ---- QK^T: sim[16q x 32s] ----
        f32x4 sim0 = (f32x4){0.f, 0.f, 0.f, 0.f};
        f32x4 sim1 = (f32x4){0.f, 0.f, 0.f, 0.f};
#pragma unroll
        for (int f = 0; f < 8; ++f) {
            const unsigned short* base = &sm.st.s1[f * 1024 + quad * 128 + l16 * 8];
            f16x8 b0 = *(const f16x8*)base;           // nt=0: true s = 2*l16
            f16x8 b1 = *(const f16x8*)(base + 512);   // nt=1: true s = 2*l16+1
            sim0 = __builtin_amdgcn_mfma_f32_16x16x32_f16(qf[f], b0, sim0, 0, 0, 0);
            sim1 = __builtin_amdgcn_mfma_f32_16x16x32_f16(qf[f], b1, sim1, 0, 0, 0);
        }

        // ---- online softmax (rows q = 16w+4quad+r; reduce over l16) ----
        float rowmax[4];
#pragma unroll
        for (int r = 0; r < 4; ++r) rowmax[r] = fmaxf(sim0[r], sim1[r]);
#pragma unroll
        for (int off = 1; off <= 8; off <<= 1)
#pragma unroll
            for (int r = 0; r < 4; ++r)
                rowmax[r] = fmaxf(rowmax[r], __shfl_xor(rowmax[r], off, 64));

        float al[4], rs[4], pv0[4], pv1[4];
#pragma unroll
        for (int r = 0; r < 4; ++r) {
            const float mn = fmaxf(m_run[r], rowmax[r]);
            al[r] = __expf(m_run[r] - mn);
            m_run[r] = mn;
            pv0[r] = __expf(sim0[r] - mn);
            pv1[r] = __expf(sim1[r] - mn);
            rs[r] = pv0[r] + pv1[r];
        }
#pragma unroll
        for (int off = 1; off <= 8; off <<= 1)
#pragma unroll
            for (int r = 0; r < 4; ++r) rs[r] += __shfl_xor(rs[r], off, 64);
#pragma unroll
        for (int r = 0; r < 4; ++r) l_run[r] = l_run[r] * al[r] + rs[r];

        // ---- publish P (fp16 pairs, b32) and alpha (pb cols 32-33) ----
#pragma unroll
        for (int r = 0; r < 4; ++r) {
            union { _Float16 h[2]; unsigned u; } pk;
            pk.h[0] = (_Float16)pv0[r];
            pk.h[1] = (_Float16)pv1[r];
            *(unsigned*)&sm.st.pb[16 * w + 4 * quad + r][l16 * 2] = pk.u;
        }
        if (l16 == 0) {
#pragma unroll
            for (int r = 0; r < 4; ++r)
                *(float*)&sm.st.pb[16 * w + 4 * quad + r][32] = al[r];
        }
        __syncthreads();

        // ---- rescale O^T, then O^T += V^T * P^T ----
#pragma unroll
        for (int nt = 0; nt < 4; ++nt) {
            const float a = *(const float*)&sm.st.pb[16 * nt + l16][32];
#pragma unroll
            for (int mt = 0; mt < 4; ++mt) {
                O[mt][nt][0] *= a; O[mt][nt][1] *= a; O[mt][nt][2] *= a; O[mt][nt][3] *= a;
            }
        }
        f16x8 vf[4], pf[4];
#pragma unroll
        for (int mt = 0; mt < 4; ++mt) {
            const int c = 64 * w + 16 * mt + l16;
            const int p = c * 4 + (quad ^ ((l16 >> 2) & 3));
            vf[mt] = *(const f16x8*)&sm.st.s2[p * 8];
        }
#pragma unroll
        for (int nt = 0; nt < 4; ++nt)
            pf[nt] = *(const f16x8*)&sm.st.pb[16 * nt + l16][quad * 8];
#pragma unroll
        for (int mt = 0; mt < 4; ++mt)
#pragma unroll
            for (int nt = 0; nt < 4; ++nt)
                O[mt][nt] = __builtin_amdgcn_mfma_f32_16x16x32_f16(vf[mt], pf[nt], O[mt][nt], 0, 0, 0);
    }

    // ---- epilogue ----
    if (l16 == 0) {
#pragma unroll
        for (int r = 0; r < 4; ++r)
            *(float*)&sm.st.pb[16 * w + 4 * quad + r][34] = l_run[r];
    }
    __syncthreads();

    float linv[4];
#pragma unroll
    for (int nt = 0; nt < 4; ++nt)
        linv[nt] = 0.2f / *(const float*)&sm.st.pb[16 * nt + l16][34];
    __syncthreads();   // all lfin reads done before epi aliases pb rows 0..25

    float* __restrict__ out2 = out + OUT2_OFF + (size_t)((g << 2) + b) * (256 * 1024);

#pragma unroll
    for (int h = 0; h < 2; ++h) {
        if ((w >> 1) == h) {
            const int we = w & 1;
#pragma unroll
            for (int mt = 0; mt < 4; ++mt)
#pragma unroll
                for (int nt = 0; nt < 4; ++nt)
#pragma unroll
                    for (int r = 0; r < 4; ++r)
                        sm.epi[we][16 * mt + 4 * quad + r][16 * nt + l16] = O[mt][nt][r] * linv[nt];
        }
        __syncthreads();
#pragma unroll 4
        for (int i = 0; i < 32; ++i) {
            const int ro = w * 32 + i;   // 0..127 -> c = 128h + ro
            const float v = sm.epi[ro >> 6][ro & 63][lane];
            atomicAdd(out2 + (size_t)(h * 128 + ro) * 1024 + q0 + lane, v);
        }
        __syncthreads();
    }
}

// ---------------------------------------------------------------------------
extern "C" void kernel_launch(void* const* d_in, const int* in_sizes, int n_in,
                              void* d_out, int out_size, void* d_ws, size_t ws_size,
                              hipStream_t stream) {
    const float* q = (const float*)d_in[0];
    const float* s = (const float*)d_in[1];
    float* out = (float*)d_out;
    float* ws = (float*)d_ws;
    unsigned short* sh = (unsigned short*)((char*)d_ws + WS_SH);
    unsigned short* sv = sh + SH_ELEMS;
    unsigned short* qt = sv + SV_ELEMS;

    hipMemsetAsync(d_ws, 0, 2 * sizeof(float), stream);

    means_kernel<<<256, 256, 0, stream>>>(q, s, ws);
    convert_kernel<<<dim3(32, 8, 14), 256, 0, stream>>>(q, s, ws, sh, sv, qt, out);
    attn_kernel<<<dim3(16, 40), 256, 0, stream>>>(qt, sh, sv, out);
}